// Round 1
// baseline (370.607 us; speedup 1.0000x reference)
//
#include <hip/hip_runtime.h>

#define BB 4
#define CC 128
#define NN 4096

typedef float f32x4 __attribute__((ext_vector_type(4)));
typedef __bf16 bf16x8 __attribute__((ext_vector_type(8)));

// ---------------------------------------------------------------------------
// Kernel 1: QKV projection (fp32 vector math, exact weights).
// Writes Qt, Kt as bf16 [B][N][C]  (contiguous c -> MFMA frag loads)
//        V       as bf16 [B][C][N] (contiguous n -> MFMA frag loads)
// ---------------------------------------------------------------------------
__global__ __launch_bounds__(512, 2)
void proj_qkv(const float* __restrict__ x,
              const float* __restrict__ Wq, const float* __restrict__ bq,
              const float* __restrict__ Wk, const float* __restrict__ bk,
              const float* __restrict__ Wv, const float* __restrict__ bv,
              __bf16* __restrict__ Qt, __bf16* __restrict__ Kt,
              __bf16* __restrict__ Vv)
{
    const int b    = blockIdx.y;
    const int n0   = blockIdx.x * 64;
    const int tid  = threadIdx.x;
    const int lane = tid & 63;
    const int wv   = __builtin_amdgcn_readfirstlane(tid >> 6); // 0..7, uniform

    __shared__ __bf16 ts[64][264]; // [n][0..127 = Q, 128..255 = K] (+8 pad)

    // one x column per lane, in registers (coalesced loads)
    float xr[CC];
    const float* xp = x + ((size_t)b * CC) * NN + n0 + lane;
#pragma unroll
    for (int c = 0; c < CC; c++) xr[c] = xp[(size_t)c * NN];

    // wave wv computes rows [wv*48, wv*48+48) of the stacked [Q;K;V] (384 rows)
    for (int r = 0; r < 48; r++) {
        int row = wv * 48 + r;
        int mat = row >> 7;      // 0=Q 1=K 2=V  (uniform)
        int o   = row & 127;
        const float* Wp = (mat == 0) ? Wq : (mat == 1) ? Wk : Wv;
        const float* bp = (mat == 0) ? bq : (mat == 1) ? bk : bv;
        const float* wr = Wp + o * CC;   // uniform -> s_load
        float acc = bp[o];
#pragma unroll
        for (int c = 0; c < CC; c++) acc += wr[c] * xr[c];
        __bf16 h = (__bf16)acc;
        if (mat < 2) ts[lane][mat * 128 + o] = h;                      // transpose staging
        else         Vv[((size_t)b * CC + o) * NN + n0 + lane] = h;    // direct, coalesced
    }
    __syncthreads();

    // coalesced write-out of transposed Q/K rows
    {
        int r   = tid >> 3;      // 0..63
        int seg = tid & 7;       // 0..7, 32 bf16 each
        const uint4* src = (const uint4*)&ts[r][seg * 32];
        __bf16* dst = (seg < 4)
            ? (Qt + ((size_t)b * NN + n0 + r) * CC + seg * 32)
            : (Kt + ((size_t)b * NN + n0 + r) * CC + (seg - 4) * 32);
        uint4* d4 = (uint4*)dst;
#pragma unroll
        for (int q = 0; q < 4; q++) d4[q] = src[q];
    }
}

// ---------------------------------------------------------------------------
// Kernel 2: flash attention, bf16 MFMA 16x16x32 (verified layouts only).
// Block = 512 thr = 8 waves: iw (i-half, 32 queries) x jw (4-way j-split).
// Each wave: online softmax over its 16 j-tiles of 64 keys; merge at end.
// ---------------------------------------------------------------------------
__global__ __launch_bounds__(512, 2)
void flash_attn(const __bf16* __restrict__ Qt, const __bf16* __restrict__ Kt,
                const __bf16* __restrict__ Vv, float* __restrict__ attn)
{
    const int blk   = blockIdx.x;
    const int xcd   = blk & 7;                       // XCD-locality swizzle:
    const int b     = xcd >> 1;                      // XCDs {2b,2b+1} <-> batch b
    const int itile = (blk >> 3) | ((xcd & 1) << 5); // 0..63
    const int i0    = itile * 64;

    const int tid  = threadIdx.x;
    const int lane = tid & 63;
    const int wv   = __builtin_amdgcn_readfirstlane(tid >> 6); // 0..7
    const int jw   = wv & 3;
    const int iw   = wv >> 2;
    const int col  = lane & 15;
    const int quad = lane >> 4;

    __shared__ __align__(16) char smem[36864];  // Ps (main loop) / Olds (merge)
    __shared__ float MLbuf[2][2][32];           // [m|l][iw][i_local]

    __bf16* Ps = (__bf16*)smem + wv * (32 * 72); // per-wave P tile [32][64+8]

    const __bf16* Qb = Qt + (size_t)b * NN * CC;
    const __bf16* Kb = Kt + (size_t)b * NN * CC;
    const __bf16* Vb = Vv + (size_t)b * CC * NN;

    const int ibase = i0 + iw * 32;

    // Q fragments, held for entire kernel: A[m=i][k=c], m=col, k=quad*8+j
    bf16x8 qf[2][4];
#pragma unroll
    for (int ig = 0; ig < 2; ig++)
#pragma unroll
        for (int ks = 0; ks < 4; ks++)
            qf[ig][ks] = *(const bf16x8*)(Qb + (size_t)(ibase + ig*16 + col) * CC
                                             + ks*32 + quad*8);

    f32x4 O[2][8];
#pragma unroll
    for (int ig = 0; ig < 2; ig++)
#pragma unroll
        for (int cg = 0; cg < 8; cg++) O[ig][cg] = (f32x4){0.f, 0.f, 0.f, 0.f};

    float m_run[2][4], l_run[2][4];
#pragma unroll
    for (int ig = 0; ig < 2; ig++)
#pragma unroll
        for (int r = 0; r < 4; r++) { m_run[ig][r] = -3.0e38f; l_run[ig][r] = 0.f; }

    for (int jt = jw; jt < 64; jt += 4) {
        const int j0 = jt * 64;

        // ---- S[i][j] = sum_c Q[i][c] K[j][c] ----
        f32x4 S[2][4];
#pragma unroll
        for (int ig = 0; ig < 2; ig++)
#pragma unroll
            for (int jg = 0; jg < 4; jg++) S[ig][jg] = (f32x4){0.f, 0.f, 0.f, 0.f};

#pragma unroll
        for (int ks = 0; ks < 4; ks++) {
            bf16x8 kf[4];  // B[k=c][n=j]: n=col, k=quad*8+jj -> Kt row contiguous
#pragma unroll
            for (int jg = 0; jg < 4; jg++)
                kf[jg] = *(const bf16x8*)(Kb + (size_t)(j0 + jg*16 + col) * CC
                                             + ks*32 + quad*8);
#pragma unroll
            for (int jg = 0; jg < 4; jg++) {
                S[0][jg] = __builtin_amdgcn_mfma_f32_16x16x32_bf16(qf[0][ks], kf[jg], S[0][jg], 0, 0, 0);
                S[1][jg] = __builtin_amdgcn_mfma_f32_16x16x32_bf16(qf[1][ks], kf[jg], S[1][jg], 0, 0, 0);
            }
        }

        // ---- online softmax (rows i = quad*4+r spread over 16 cols=lanes) ----
        float mx[2][4];
#pragma unroll
        for (int ig = 0; ig < 2; ig++)
#pragma unroll
            for (int r = 0; r < 4; r++) {
                float v = fmaxf(fmaxf(S[ig][0][r], S[ig][1][r]),
                                fmaxf(S[ig][2][r], S[ig][3][r]));
                mx[ig][r] = v;
            }
#pragma unroll
        for (int st = 1; st < 16; st <<= 1)
#pragma unroll
            for (int ig = 0; ig < 2; ig++)
#pragma unroll
                for (int r = 0; r < 4; r++)
                    mx[ig][r] = fmaxf(mx[ig][r], __shfl_xor(mx[ig][r], st));

        float alpha[2][4], rs[2][4];
#pragma unroll
        for (int ig = 0; ig < 2; ig++)
#pragma unroll
            for (int r = 0; r < 4; r++) {
                float mn = fmaxf(m_run[ig][r], mx[ig][r]);
                alpha[ig][r] = __expf(m_run[ig][r] - mn);
                m_run[ig][r] = mn;
                rs[ig][r] = 0.f;
            }
#pragma unroll
        for (int ig = 0; ig < 2; ig++)
#pragma unroll
            for (int jg = 0; jg < 4; jg++)
#pragma unroll
                for (int r = 0; r < 4; r++) {
                    float p = __expf(S[ig][jg][r] - m_run[ig][r]);
                    S[ig][jg][r] = p;
                    rs[ig][r] += p;
                }
#pragma unroll
        for (int st = 1; st < 16; st <<= 1)
#pragma unroll
            for (int ig = 0; ig < 2; ig++)
#pragma unroll
                for (int r = 0; r < 4; r++)
                    rs[ig][r] += __shfl_xor(rs[ig][r], st);
#pragma unroll
        for (int ig = 0; ig < 2; ig++)
#pragma unroll
            for (int r = 0; r < 4; r++)
                l_run[ig][r] = l_run[ig][r] * alpha[ig][r] + rs[ig][r];

        // rescale O accumulator
#pragma unroll
        for (int ig = 0; ig < 2; ig++)
#pragma unroll
            for (int cg = 0; cg < 8; cg++)
#pragma unroll
                for (int r = 0; r < 4; r++)
                    O[ig][cg][r] *= alpha[ig][r];

        // P -> LDS (C/D layout -> row-major [i][j]), wave-private, no barrier
#pragma unroll
        for (int ig = 0; ig < 2; ig++)
#pragma unroll
            for (int jg = 0; jg < 4; jg++)
#pragma unroll
                for (int r = 0; r < 4; r++)
                    Ps[(ig*16 + quad*4 + r) * 72 + jg*16 + col] = (__bf16)S[ig][jg][r];

        // ---- O[i][c] += sum_j P[i][j] V[c][j] ----
#pragma unroll
        for (int ks2 = 0; ks2 < 2; ks2++) {
            bf16x8 pf[2];  // A[m=i][k=j]
#pragma unroll
            for (int ig = 0; ig < 2; ig++)
                pf[ig] = *(const bf16x8*)(Ps + (ig*16 + col) * 72 + ks2*32 + quad*8);
#pragma unroll
            for (int cg = 0; cg < 8; cg++) {
                bf16x8 vf = *(const bf16x8*)(Vb + (size_t)(cg*16 + col) * NN
                                                + j0 + ks2*32 + quad*8);
                O[0][cg] = __builtin_amdgcn_mfma_f32_16x16x32_bf16(pf[0], vf, O[0][cg], 0, 0, 0);
                O[1][cg] = __builtin_amdgcn_mfma_f32_16x16x32_bf16(pf[1], vf, O[1][cg], 0, 0, 0);
            }
        }
    }

    // ---- merge 4 j-split partials per iw half (sequential rescaled sum) ----
    __syncthreads();                         // done with Ps region
    float* Olds = (float*)smem + iw * 4224;  // [128][33] fp32 per iw half

    for (int w = 0; w < 4; w++) {
        if (jw == w) {
            if (w == 0) {
#pragma unroll
                for (int ig = 0; ig < 2; ig++)
#pragma unroll
                    for (int cg = 0; cg < 8; cg++)
#pragma unroll
                        for (int r = 0; r < 4; r++)
                            Olds[(cg*16 + col) * 33 + ig*16 + quad*4 + r] = O[ig][cg][r];
                if (col == 0) {
#pragma unroll
                    for (int ig = 0; ig < 2; ig++)
#pragma unroll
                        for (int r = 0; r < 4; r++) {
                            MLbuf[0][iw][ig*16 + quad*4 + r] = m_run[ig][r];
                            MLbuf[1][iw][ig*16 + quad*4 + r] = l_run[ig][r];
                        }
                }
            } else {
                float aold[2][4], anew[2][4], mnew[2][4];
#pragma unroll
                for (int ig = 0; ig < 2; ig++)
#pragma unroll
                    for (int r = 0; r < 4; r++) {
                        float Mo = MLbuf[0][iw][ig*16 + quad*4 + r];
                        float mt = fmaxf(Mo, m_run[ig][r]);
                        aold[ig][r] = __expf(Mo - mt);
                        anew[ig][r] = __expf(m_run[ig][r] - mt);
                        mnew[ig][r] = mt;
                    }
#pragma unroll
                for (int ig = 0; ig < 2; ig++)
#pragma unroll
                    for (int cg = 0; cg < 8; cg++)
#pragma unroll
                        for (int r = 0; r < 4; r++) {
                            int idx = (cg*16 + col) * 33 + ig*16 + quad*4 + r;
                            Olds[idx] = Olds[idx] * aold[ig][r] + anew[ig][r] * O[ig][cg][r];
                        }
                if (col == 0) {
#pragma unroll
                    for (int ig = 0; ig < 2; ig++)
#pragma unroll
                        for (int r = 0; r < 4; r++) {
                            int il = ig*16 + quad*4 + r;
                            MLbuf[1][iw][il] = MLbuf[1][iw][il] * aold[ig][r]
                                             + l_run[ig][r] * anew[ig][r];
                            MLbuf[0][iw][il] = mnew[ig][r];
                        }
                }
            }
        }
        __syncthreads();
    }

    // ---- normalize + write attn[b][c][n]  (fp32, [B][C][N]) ----
    {
        const int t2  = tid & 255;
        const int iw2 = tid >> 8;
        float* Ol = (float*)smem + iw2 * 4224;
#pragma unroll
        for (int e = 0; e < 16; e++) {
            int flat = e * 256 + t2;
            int c  = flat >> 5;
            int il = flat & 31;
            attn[((size_t)b * CC + c) * NN + i0 + iw2 * 32 + il] =
                Ol[c * 33 + il] / MLbuf[1][iw2][il];
        }
    }
}

// ---------------------------------------------------------------------------
// Kernel 3: out = Wo @ (gamma*attn + x) + bo   (fp32 vector, fused residual)
// ---------------------------------------------------------------------------
__global__ __launch_bounds__(512, 2)
void proj_out(const float* __restrict__ attn, const float* __restrict__ x,
              const float* __restrict__ Wo, const float* __restrict__ bo,
              const float* __restrict__ gamma, float* __restrict__ out)
{
    const int b    = blockIdx.y;
    const int n0   = blockIdx.x * 64;
    const int tid  = threadIdx.x;
    const int lane = tid & 63;
    const int wv   = __builtin_amdgcn_readfirstlane(tid >> 6);

    const float g = gamma[0];
    float sa[CC];
    const float* xp = x    + (size_t)b * CC * NN + n0 + lane;
    const float* ap = attn + (size_t)b * CC * NN + n0 + lane;
#pragma unroll
    for (int c = 0; c < CC; c++) sa[c] = xp[(size_t)c * NN] + g * ap[(size_t)c * NN];

    for (int k = 0; k < 16; k++) {
        int o = wv * 16 + k;
        const float* wr = Wo + o * CC;   // uniform -> s_load
        float acc = bo[o];
#pragma unroll
        for (int c = 0; c < CC; c++) acc += wr[c] * sa[c];
        out[((size_t)b * CC + o) * NN + n0 + lane] = acc;
    }
}

// ---------------------------------------------------------------------------
extern "C" void kernel_launch(void* const* d_in, const int* in_sizes, int n_in,
                              void* d_out, int out_size, void* d_ws, size_t ws_size,
                              hipStream_t stream)
{
    const float* x  = (const float*)d_in[0];
    const float* Wq = (const float*)d_in[1];
    const float* bq = (const float*)d_in[2];
    const float* Wk = (const float*)d_in[3];
    const float* bk = (const float*)d_in[4];
    const float* Wv = (const float*)d_in[5];
    const float* bv = (const float*)d_in[6];
    const float* gm = (const float*)d_in[7];
    const float* Wo = (const float*)d_in[8];
    const float* bo = (const float*)d_in[9];

    __bf16* Qt  = (__bf16*)d_ws;                       // [B][N][C] bf16, 4 MB
    __bf16* Kt  = Qt + (size_t)BB * NN * CC;           // 4 MB
    __bf16* Vv  = Kt + (size_t)BB * NN * CC;           // [B][C][N] bf16, 4 MB
    float*  att = (float*)(Vv + (size_t)BB * NN * CC); // [B][C][N] fp32, 8 MB
    float*  out = (float*)d_out;

    proj_qkv<<<dim3(64, 4), 512, 0, stream>>>(x, Wq, bq, Wk, bk, Wv, bv, Qt, Kt, Vv);
    flash_attn<<<256, 512, 0, stream>>>(Qt, Kt, Vv, att);
    proj_out<<<dim3(64, 4), 512, 0, stream>>>(att, x, Wo, bo, gm, out);
}